// Round 6
// baseline (376.666 us; speedup 1.0000x reference)
//
#include <hip/hip_runtime.h>
#include <math.h>

// One thread per row (B = 1e6, 24 f32 in, 48+32 f32 out).
// Memory floor: 416 B/row -> ~66 us at 6.3 TB/s (kernel only).
//
// R6 changes (vs R5):
//  - wave-autonomous, ZERO __syncthreads: each wave stages its own 64 rows
//    (384 f4, contiguous) into a private LDS slice, computes, stores. LDS
//    ordering within a wave is program order + compiler lgkmcnt (+
//    wave_barrier as a scheduling fence). Removes the block-wide phase
//    correlation that left HBM idle between load/store surges.
//  - stores back to NORMAL cached (the 6.29 TB/s fill uses normal stores;
//    nt stores may ack only after deeper drain). nt kept on loads only.
//  - LDS slice reused for output pattern values (inputs fully consumed
//    first; in-order wave execution makes this safe): 25 KB/block
//    -> 6 blocks/CU (24 waves/CU, was 16).
//  - j-stride padded 64->65 to break the 6-way phase-1 ds_write conflict.
//
// Compute path is bit-exact numpy f32 (verified R2/R3/R5, absmax 3.9e-3):
//  - no FMA contraction, sqrt'd distance compare, IEEE div,
//    left-associated reductions, numpy ddof=1 re-centered std.

#define TPB 256
#define WAVES (TPB / 64)
#define SLICE 390  // 6*65 f4 per wave (j-major, stride 65)

typedef float vfloat4 __attribute__((ext_vector_type(4)));

__global__ __launch_bounds__(TPB) void speaker_kernel(
    const float* __restrict__ in, float* __restrict__ out, int B) {
#pragma clang fp contract(off)
  __shared__ vfloat4 lds[WAVES * SLICE];  // 24.96 KB

  const int t = threadIdx.x;
  const int lane = t & 63;
  const int w = t >> 6;
  const int waveRow0 = blockIdx.x * TPB + w * 64;  // first row of this wave
  const int rowsInWave = min(64, B - waveRow0);    // may be <=0 for tail waves
  vfloat4* slice = lds + w * SLICE;

  // ---- Phase 1: wave's 64 rows (contiguous 6 KB) -> j-major LDS ----
  {
    const vfloat4* gin = (const vfloat4*)in + (size_t)waveRow0 * 6;
#pragma unroll
    for (int k = 0; k < 6; ++k) {
      int g = k * 64 + lane;   // 0..383 f4 within wave chunk
      int row = g / 6;         // local row 0..63
      int j = g - row * 6;     // 0..5
      if (row < rowsInWave)
        slice[j * 65 + row] = __builtin_nontemporal_load(gin + g);
    }
  }
  __builtin_amdgcn_wave_barrier();  // compiler scheduling fence (intra-wave)

  // ---- Phase 2: per-row compute (bit-exact numpy f32) ----
  const bool active = lane < rowsInWave;
  vfloat4 A, Bv, C;
  if (active) {
    float r[24];
#pragma unroll
    for (int j = 0; j < 6; ++j) {
      vfloat4 v = slice[j * 65 + lane];  // lane-contiguous b128
      r[4 * j + 0] = v.x;
      r[4 * j + 1] = v.y;
      r[4 * j + 2] = v.z;
      r[4 * j + 3] = v.w;
    }

    float px[4], py[4], vx[4], vy[4], q[4];
#pragma unroll
    for (int i = 0; i < 4; ++i) {
      px[i] = r[5 * i + 0];
      py[i] = r[5 * i + 1];
      vx[i] = r[5 * i + 2];
      vy[i] = r[5 * i + 3];
      q[i]  = r[5 * i + 4];
    }
    float gx = r[20], gy = r[21], gq = r[22], gm = r[23];

    float gn  = sqrtf(gx * gx + gy * gy);
    float den = fmaxf(gn, 1e-12f);
    float gpx = gx / den;
    float gpy = gy / den;

    float sgn = (gm > 0.0f) ? 1.0f : ((gm < 0.0f) ? -1.0f : 0.0f);

    float ax = (((px[0] + px[1]) + px[2]) + px[3]) / 4.0f;
    float ay = (((py[0] + py[1]) + py[2]) + py[3]) / 4.0f;

    float s[4];
#pragma unroll
    for (int i = 0; i < 4; ++i) {
      float best = 3.0e38f;
      float vnx = 0.0f, vny = 0.0f;
#pragma unroll
      for (int j = 0; j < 4; ++j) {
        float dj;
        if (j == i) {
          dj = 100.0f;  // sqrt(0) + 100 diag mask
        } else {
          float dx = px[i] - px[j];
          float dy = py[i] - py[j];
          dj = sqrtf(dx * dx + dy * dy);
        }
        if (dj < best) { best = dj; vnx = vx[j]; vny = vy[j]; }
      }
      float pos_score = (px[i] * gpx) + (py[i] * gpy);
      float q_score   = q[i] * gq;
      float va        = ((vx[i] * vnx) + (vy[i] * vny)) * gm;
      float dxa = px[i] - ax;
      float dya = py[i] - ay;
      float rel = (-sqrtf(dxa * dxa + dya * dya)) * sgn;
      float u0 = 0.25f * pos_score;
      float u1 = 1.15f * q_score;
      float u2 = 0.9f * va;
      float u3 = 0.15f * rel;
      s[i] = ((u0 + u1) + u2) + u3;
    }

    float mean = (((s[0] + s[1]) + s[2]) + s[3]) / 4.0f;
    float c0 = s[0] - mean, c1 = s[1] - mean, c2 = s[2] - mean, c3 = s[3] - mean;

    float m2 = (((c0 + c1) + c2) + c3) / 4.0f;
    float x0 = c0 - m2, x1 = c1 - m2, x2 = c2 - m2, x3 = c3 - m2;
    float var = ((((x0 * x0) + (x1 * x1)) + (x2 * x2)) + (x3 * x3)) / 3.0f;
    float std = sqrtf(var);
    float dn  = fmaxf(std, 1e-4f);

    float t0 = tanhf(c0 / dn);
    float t1 = tanhf(c1 / dn);
    float t2 = tanhf(c2 / dn);
    float t3 = tanhf(c3 / dn);
    float t4 = tanhf(gq);
    float t5 = tanhf(gm);

    A  = (vfloat4){t0, t1, t2, t3};
    Bv = (vfloat4){t4, t5, t0, t1};
    C  = (vfloat4){t2, t3, t4, t5};
  }

  __builtin_amdgcn_wave_barrier();  // all input reads precede st writes

  // reuse slice for pattern values: lane-major, 3 f4/row (inputs consumed)
  if (active) {
    slice[lane * 3 + 0] = A;
    slice[lane * 3 + 1] = Bv;
    slice[lane * 3 + 2] = C;
  }
  __builtin_amdgcn_wave_barrier();

  // ---- Phase 3: coalesced cached stores (normal, not nt) ----
  // comm: wave region = rowsInWave*12 f4; pattern (o%12)%3 == o%3
  {
    vfloat4* oc = (vfloat4*)out + (size_t)waveRow0 * 12;
    const int nc = rowsInWave * 12;
#pragma unroll
    for (int k = 0; k < 12; ++k) {
      int o = k * 64 + lane;  // 0..767
      if (o < nc) {
        int row = o / 12;
        int pat = o % 3;
        oc[o] = slice[row * 3 + pat];
      }
    }
  }
  // state: wave region = rowsInWave*8 f4; pattern (o%8)%3
  {
    vfloat4* os = (vfloat4*)out + (size_t)B * 12 + (size_t)waveRow0 * 8;
    const int ns = rowsInWave * 8;
#pragma unroll
    for (int k = 0; k < 8; ++k) {
      int o = k * 64 + lane;  // 0..511
      if (o < ns) {
        int row = o >> 3;
        int pat = (o & 7) % 3;
        os[o] = slice[row * 3 + pat];
      }
    }
  }
}

extern "C" void kernel_launch(void* const* d_in, const int* in_sizes, int n_in,
                              void* d_out, int out_size, void* d_ws, size_t ws_size,
                              hipStream_t stream) {
  const float* in = (const float*)d_in[0];
  float* out = (float*)d_out;
  int B = in_sizes[0] / 24;
  int blocks = (B + TPB - 1) / TPB;
  speaker_kernel<<<blocks, TPB, 0, stream>>>(in, out, B);
}